// Round 3
// baseline (133.917 us; speedup 1.0000x reference)
//
#include <hip/hip_runtime.h>
#include <math.h>

#define NPAIRS 262144
#define D4     32                 // 128 floats = 32 float4 per row
#define TPB    256
#define NBLK   2048
#define GPB    (TPB / 32)         // 8 groups of 32 lanes per block
#define PPB    (NPAIRS / NBLK)    // 128 contiguous pos pairs per block
#define PPG    (PPB / GPB)        // 16 pos pairs per group
#define NGROUPS ((NBLK * TPB) / 32)       // 16384
#define NEG_ITERS (NPAIRS / NGROUPS)      // 16

// 32-lane group per pair; lane l holds float4 #l of each row (512B coalesced).
//
// Pos pairs: pos_idx is sorted by i (np.nonzero row-major) -> runs of ~63
// pairs share row i. Blocks take CONTIGUOUS 128-pair chunks, groups
// interleave stride-8 inside, so the a-row stays hot in the CU's L1 across
// groups and iterations. Squared distance is separable over dims, so lanes
// accumulate private partials -- no per-pair shuffle.
//
// Neg pairs: uniform-random indices (no locality) -> grid-stride like R1.
//
// Both loops: 1 pair per iteration (small body, compiler can pipeline) with
// EXPLICIT next-idx prefetch (pow2 wrap) to break the idx->gather serial
// dependency.
__global__ __launch_bounds__(TPB) void pair_kernel(
    const float* __restrict__ X,
    const int2*  __restrict__ pos2,
    const int2*  __restrict__ neg2,
    const float* __restrict__ h_bias,
    float* __restrict__ out)
{
    const int lane    = threadIdx.x & 31;
    const int group   = threadIdx.x >> 5;
    const int gid     = (blockIdx.x * TPB + threadIdx.x) >> 5;
    const int ngroups = (gridDim.x * TPB) >> 5;   // 16384

    const float4* __restrict__ X4 = (const float4*)X;

    // numerically stable softplus(h_bias)
    const float hb   = h_bias[0];
    const float bias = fmaxf(hb, 0.0f) + log1pf(expf(-fabsf(hb)));

    // ---------------- positive pairs: contiguous per block, no shuffles ----
    float posAcc = 0.0f;
    {
        const int base = blockIdx.x * PPB + group;
        int2 ij = pos2[base];
        for (int t = 0; t < PPG; ++t) {
            const int2 nij = pos2[base + ((t + 1) & (PPG - 1)) * GPB]; // prefetch (wraps to base on last iter)
            const float4 a = X4[ij.x * D4 + lane];
            const float4 b = X4[ij.y * D4 + lane];
            float d;
            d = a.x - b.x; posAcc = fmaf(d, d, posAcc);
            d = a.y - b.y; posAcc = fmaf(d, d, posAcc);
            d = a.z - b.z; posAcc = fmaf(d, d, posAcc);
            d = a.w - b.w; posAcc = fmaf(d, d, posAcc);
            ij = nij;
        }
    }

    // ---------------- negative pairs: grid-stride, per-pair reduce ---------
    float negAcc = 0.0f;
    {
        int2 ij = neg2[gid];
        for (int t = 0; t < NEG_ITERS; ++t) {
            const int2 nij = neg2[gid + ((t + 1) & (NEG_ITERS - 1)) * ngroups]; // prefetch
            const float4 a = X4[ij.x * D4 + lane];
            const float4 b = X4[ij.y * D4 + lane];
            float d, s = 0.0f;
            d = a.x - b.x; s = fmaf(d, d, s);
            d = a.y - b.y; s = fmaf(d, d, s);
            d = a.z - b.z; s = fmaf(d, d, s);
            d = a.w - b.w; s = fmaf(d, d, s);
            #pragma unroll
            for (int m = 16; m > 0; m >>= 1) s += __shfl_xor(s, m, 32);
            float r = fmaxf(bias - sqrtf(s), 0.0f);
            negAcc = fmaf(r, r, negAcc);
            ij = nij;
        }
    }
    // negAcc is group-uniform (every lane accumulated identical values).

    // reduce posAcc across the 32-lane group
    #pragma unroll
    for (int m = 16; m > 0; m >>= 1) posAcc += __shfl_xor(posAcc, m, 32);

    __shared__ float sp[GPB], sn[GPB];
    if (lane == 0) { sp[group] = posAcc; sn[group] = negAcc; }
    __syncthreads();
    if (threadIdx.x == 0) {
        float P = 0.f, Nn = 0.f;
        #pragma unroll
        for (int g = 0; g < GPB; ++g) { P += sp[g]; Nn += sn[g]; }
        atomicAdd(&out[0], P  * (0.5f / NPAIRS));
        atomicAdd(&out[1], Nn * (0.5f / NPAIRS));
    }
}

extern "C" void kernel_launch(void* const* d_in, const int* in_sizes, int n_in,
                              void* d_out, int out_size, void* d_ws, size_t ws_size,
                              hipStream_t stream) {
    const float* X       = (const float*)d_in[0];
    // d_in[1] = scores (unused), d_in[3] = labels (unused)
    const float* h_bias  = (const float*)d_in[2];
    const int2*  pos2    = (const int2*)d_in[4];
    const int2*  neg2    = (const int2*)d_in[5];
    float*       out     = (float*)d_out;

    hipMemsetAsync(out, 0, (size_t)out_size * sizeof(float), stream);
    pair_kernel<<<NBLK, TPB, 0, stream>>>(X, pos2, neg2, h_bias, out);
}

// Round 4
// 89.330 us; speedup vs baseline: 1.4991x; 1.4991x over previous
//
#include <hip/hip_runtime.h>
#include <math.h>

#define NPAIRS  262144
#define D4      32                  // 128 floats = 32 float4 per row
#define TPB     256
#define NBLK    2048
#define GPB     (TPB / 32)          // 8 groups per block
#define NGROUPS (NBLK * GPB)        // 16384
#define PPG     (NPAIRS / NGROUPS)  // 16 pairs per group per list

// 32-lane group per pair; lane l holds float4 #l of each row (512B coalesced).
//
// Each group takes 16 CONSECUTIVE pairs from each list. Its 16 int2 indices
// (128 B) are preloaded with ONE coalesced dword-per-lane load; per-iteration
// (i,j) come from __shfl broadcast (no memory latency, no per-iter idx load).
// Consecutive pos pairs share i (np.nonzero row-major runs of ~63), so the
// a-row stays hot in L1 across the group's iterations.
//
// Pos: squared distance is separable over dims -> lanes accumulate private
// partials, ONE butterfly at the end. Neg: per-pair butterfly + margin.
//
// Reduction: per-block partials to d_ws + finalize kernel. R2/R3 lesson:
// 2048-block atomicAdd to the SAME two addresses serializes at the TCC
// (~25us tail) -- never again.
__global__ __launch_bounds__(TPB, 4) void pair_kernel(
    const float* __restrict__ X,
    const int*   __restrict__ pos_i,   // pos_idx as flat int stream
    const int*   __restrict__ neg_i,   // neg_idx as flat int stream
    const float* __restrict__ h_bias,
    float* __restrict__ partials)
{
    const int lane  = threadIdx.x & 31;
    const int group = threadIdx.x >> 5;
    const int gid   = (blockIdx.x * TPB + threadIdx.x) >> 5;

    const float4* __restrict__ X4 = (const float4*)X;

    // numerically stable softplus(h_bias)
    const float hb   = h_bias[0];
    const float bias = fmaxf(hb, 0.0f) + log1pf(expf(-fabsf(hb)));

    // Preload this group's 16 pairs from each list: 32 ints = 128 B,
    // one dword per lane, fully coalesced.
    const int pidx = pos_i[gid * 32 + lane];
    const int nidx = neg_i[gid * 32 + lane];

    // ---------------- positive pairs: separable, no per-pair reduce --------
    float posAcc = 0.0f;
    #pragma unroll
    for (int t = 0; t < PPG; ++t) {
        const int i = __shfl(pidx, 2 * t,     32);
        const int j = __shfl(pidx, 2 * t + 1, 32);
        const float4 a = X4[i * D4 + lane];
        const float4 b = X4[j * D4 + lane];
        float d;
        d = a.x - b.x; posAcc = fmaf(d, d, posAcc);
        d = a.y - b.y; posAcc = fmaf(d, d, posAcc);
        d = a.z - b.z; posAcc = fmaf(d, d, posAcc);
        d = a.w - b.w; posAcc = fmaf(d, d, posAcc);
    }

    // ---------------- negative pairs: per-pair butterfly + margin ----------
    float negAcc = 0.0f;
    #pragma unroll
    for (int t = 0; t < PPG; ++t) {
        const int i = __shfl(nidx, 2 * t,     32);
        const int j = __shfl(nidx, 2 * t + 1, 32);
        const float4 a = X4[i * D4 + lane];
        const float4 b = X4[j * D4 + lane];
        float d, s = 0.0f;
        d = a.x - b.x; s = fmaf(d, d, s);
        d = a.y - b.y; s = fmaf(d, d, s);
        d = a.z - b.z; s = fmaf(d, d, s);
        d = a.w - b.w; s = fmaf(d, d, s);
        #pragma unroll
        for (int m = 16; m > 0; m >>= 1) s += __shfl_xor(s, m, 32);
        const float r = fmaxf(bias - sqrtf(s), 0.0f);
        negAcc = fmaf(r, r, negAcc);
    }
    // negAcc is group-uniform after the butterflies.

    // reduce posAcc across the 32-lane group
    #pragma unroll
    for (int m = 16; m > 0; m >>= 1) posAcc += __shfl_xor(posAcc, m, 32);

    __shared__ float sp[GPB], sn[GPB];
    if (lane == 0) { sp[group] = posAcc; sn[group] = negAcc; }
    __syncthreads();
    if (threadIdx.x == 0) {
        float P = 0.f, Nn = 0.f;
        #pragma unroll
        for (int g = 0; g < GPB; ++g) { P += sp[g]; Nn += sn[g]; }
        partials[2 * blockIdx.x]     = P;
        partials[2 * blockIdx.x + 1] = Nn;
    }
}

__global__ __launch_bounds__(TPB) void finalize_kernel(
    const float* __restrict__ partials, float* __restrict__ out)
{
    __shared__ float sp[TPB], sn[TPB];
    float p = 0.0f, n = 0.0f;
    for (int b = threadIdx.x; b < NBLK; b += TPB) {
        p += partials[2 * b];
        n += partials[2 * b + 1];
    }
    sp[threadIdx.x] = p; sn[threadIdx.x] = n;
    __syncthreads();
    for (int s = TPB / 2; s > 0; s >>= 1) {
        if ((int)threadIdx.x < s) {
            sp[threadIdx.x] += sp[threadIdx.x + s];
            sn[threadIdx.x] += sn[threadIdx.x + s];
        }
        __syncthreads();
    }
    if (threadIdx.x == 0) {
        out[0] = 0.5f * sp[0] / (float)NPAIRS;
        out[1] = 0.5f * sn[0] / (float)NPAIRS;
    }
}

extern "C" void kernel_launch(void* const* d_in, const int* in_sizes, int n_in,
                              void* d_out, int out_size, void* d_ws, size_t ws_size,
                              hipStream_t stream) {
    const float* X      = (const float*)d_in[0];
    // d_in[1] = scores (unused), d_in[3] = labels (unused)
    const float* h_bias = (const float*)d_in[2];
    const int*   pos_i  = (const int*)d_in[4];
    const int*   neg_i  = (const int*)d_in[5];
    float*       out    = (float*)d_out;
    float*       partials = (float*)d_ws;   // 2048*2 floats, fully written by pair_kernel

    pair_kernel<<<NBLK, TPB, 0, stream>>>(X, pos_i, neg_i, h_bias, partials);
    finalize_kernel<<<1, TPB, 0, stream>>>(partials, out);
}